// Round 8
// baseline (36331.464 us; speedup 1.0000x reference)
//
#include <hip/hip_runtime.h>
#include <hip/hip_bf16.h>

typedef __hip_bfloat16 bf16;

constexpr int NV = 1024, TT = 24, BB = 8, CAP = 80;

// ---- ws layout (float offsets) ----
constexpr int O_H    = 0;          // [b][64][n]
constexpr int O_U    = 524288;     // [b][64][n]
constexpr int O_STATS= 1048576;    // 16
constexpr int O_CVAL = 1048592;    // [2*1024][CAP]
constexpr int O_CIDX = 1212432;
constexpr int O_CCNT = 1376272;    // 2048
constexpr int O_X1   = 1378320;    // [b][n]
constexpr int O_X2   = 1386512;
constexpr int O_T1   = 1394704;    // xin -> gcv   [b][64][n]
constexpr int O_T2   = 1918992;    // P  -> out
constexpr int O_T3   = 2443280;    // Q
constexpr int O_XH   = 2967568;    // [b][66][n]
constexpr int O_XC   = 3508240;
constexpr int O_Z1F  = 4048912;
constexpr int O_Z1B  = 4589584;
constexpr int O_Z2F  = 5130256;
constexpr int O_Z2B  = 5670928;
constexpr int O_RST  = 6211600;    // bf16 staging [t][b][n][128]
constexpr int O_SST  = 18794512;   // bf16 staging [t][b][n][64]
constexpr size_t WS_FLOATS = 25085968;

// ---- output layout (f32 elements) ----
constexpr int OFF_IMP  = 0;
constexpr int OFF_PRED = 196608;
constexpr int OFF_REPR = 393216;
constexpr int OFF_ST   = 25559040;

__device__ __forceinline__ bf16 f2b(float v){ return __float2bfloat16(v); }
__device__ __forceinline__ float b2f(bf16 v){ return __bfloat162float(v); }

__global__ __launch_bounds__(256) void k_csr(const float* __restrict__ adj, float* __restrict__ ws){
  int row = blockIdx.x*blockDim.x + threadIdx.x;
  if(row >= 2*NV) return;
  const float* a = adj + (size_t)row*NV;
  float* val = ws + O_CVAL + (size_t)row*CAP;
  int*   idx = (int*)(ws + O_CIDX) + (size_t)row*CAP;
  int cnt = 0;
  for(int v=0; v<NV; ++v){
    float av = a[v];
    if(av != 0.f && cnt < CAP){ idx[cnt] = v; val[cnt] = av; cnt++; }
  }
  ((int*)(ws + O_CCNT))[row] = cnt;
}

__global__ __launch_bounds__(256) void k_h0(const float* __restrict__ h0, float* __restrict__ ws){
  int i = blockIdx.x*blockDim.x + threadIdx.x;
  if(i >= BB*64*NV) return;
  int c = (i>>10)&63, n = i&1023;
  ws[O_H + i] = h0[c*NV + n];
}

// pred = fs_W·h + fs_b ; x1 = m>0 ? x : pred
__global__ __launch_bounds__(256) void k_pred(float* __restrict__ ws, const float* __restrict__ x,
    const float* __restrict__ mask, const float* __restrict__ fsW, const float* __restrict__ fsb,
    float* __restrict__ dout, int t){
  int g = blockIdx.x*blockDim.x + threadIdx.x;
  if(g >= BB*NV) return;
  int b = g>>10, n = g&1023;
  float s = fsb[0];
  for(int c=0;c<64;++c) s += fsW[c] * ws[O_H + ((size_t)(b*64+c))*NV + n];
  dout[OFF_PRED + (size_t)g*TT + t] = s;
  float m = mask[(size_t)g*TT + t];
  ws[O_X1 + g] = (m > 0.f) ? x[(size_t)g*TT + t] : s;
}

__global__ __launch_bounds__(256) void k_xin(float* __restrict__ ws, const float* __restrict__ mask,
    const float* __restrict__ liW, const float* __restrict__ lib, int t){
  int g = blockIdx.x*blockDim.x + threadIdx.x;
  if(g >= BB*64*NV) return;
  int b = g>>16, c = (g>>10)&63, n = g&1023;
  float m = mask[(size_t)(b*NV+n)*TT + t];
  float acc = lib[c] + liW[c*66+0]*ws[O_X1 + b*NV + n] + liW[c*66+1]*m;
  for(int j=0;j<64;++j) acc += liW[c*66+2+j] * ws[O_H + ((size_t)(b*64+j))*NV + n];
  ws[O_T1 + g] = acc;
}

__global__ __launch_bounds__(256) void k_sprop64(float* __restrict__ ws){
  int g = blockIdx.x*blockDim.x + threadIdx.x;
  if(g >= BB*64*NV) return;
  int b = g>>16, c = (g>>10)&63, w = g&1023;
  const int* ccnt = (const int*)(ws + O_CCNT);
  const float* src = ws + O_T1 + (size_t)(b*64+c)*NV;
  float p = 0.f, q = 0.f;
  { int cn = ccnt[w];
    const int* id = (const int*)(ws+O_CIDX) + (size_t)w*CAP;
    const float* vl = ws + O_CVAL + (size_t)w*CAP;
    for(int k=0;k<cn;++k) p += vl[k]*src[id[k]]; }
  { int cn = ccnt[NV+w];
    const int* id = (const int*)(ws+O_CIDX) + (size_t)(NV+w)*CAP;
    const float* vl = ws + O_CVAL + (size_t)(NV+w)*CAP;
    for(int k=0;k<cn;++k) q += vl[k]*src[id[k]]; }
  ws[O_T2 + g] = p;
  ws[O_T3 + g] = q;
}

__global__ __launch_bounds__(256) void k_gc(float* __restrict__ ws, const float* __restrict__ gcW,
                                            const float* __restrict__ gcb){
  int g = blockIdx.x*blockDim.x + threadIdx.x;
  if(g >= BB*64*NV) return;
  int b = g>>16, c = (g>>10)&63, n = g&1023;
  float acc = gcb[c];
  for(int j=0;j<64;++j){
    acc += gcW[c*128+j]    * ws[O_T2 + ((size_t)(b*64+j))*NV + n];
    acc += gcW[c*128+64+j] * ws[O_T3 + ((size_t)(b*64+j))*NV + n];
  }
  ws[O_T1 + g] = acc;
}

__global__ __launch_bounds__(256) void k_lo(float* __restrict__ ws, const float* __restrict__ loW,
    const float* __restrict__ lob, const float* __restrict__ prelu, int t){
  int g = blockIdx.x*blockDim.x + threadIdx.x;
  if(g >= BB*64*NV) return;
  int b = g>>16, c = (g>>10)&63, n = g&1023;
  float acc = lob[c];
  for(int j=0;j<64;++j){
    acc += loW[c*128+j]    * ws[O_T1 + ((size_t)(b*64+j))*NV + n];
    acc += loW[c*128+64+j] * ws[O_H  + ((size_t)(b*64+j))*NV + n];
  }
  float a = prelu[0];
  float o = (acc >= 0.f) ? acc : a*acc;
  ws[O_T2 + g] = o;
  bf16* reprs = (bf16*)(ws + O_RST);
  size_t rb = (((size_t)t*BB + b)*NV + n)*128;
  reprs[rb + c]      = f2b(o);
  reprs[rb + 64 + c] = f2b(ws[O_H + ((size_t)(b*64+c))*NV + n]);
}

// xs2 -> imp (f32) ; x2 for GRU
__global__ __launch_bounds__(256) void k_ro(float* __restrict__ ws, const float* __restrict__ x,
    const float* __restrict__ mask, const float* __restrict__ roW, const float* __restrict__ rob,
    float* __restrict__ dout, int t){
  int g = blockIdx.x*blockDim.x + threadIdx.x;
  if(g >= BB*NV) return;
  int b = g>>10, n = g&1023;
  float s = rob[0];
  for(int j=0;j<64;++j){
    s += roW[j]    * ws[O_T2 + ((size_t)(b*64+j))*NV + n];
    s += roW[64+j] * ws[O_H  + ((size_t)(b*64+j))*NV + n];
  }
  dout[OFF_IMP + (size_t)g*TT + t] = s;
  float m = mask[(size_t)g*TT + t];
  ws[O_X2 + g] = (m > 0.f) ? x[(size_t)g*TT + t] : s;
}

__global__ __launch_bounds__(256) void k_xh(float* __restrict__ ws, const float* __restrict__ mask, int t){
  int g = blockIdx.x*blockDim.x + threadIdx.x;
  if(g >= BB*66*NV) return;
  int b = g/(66*NV); int rem = g - b*66*NV; int k = rem>>10, n = rem&1023;
  float v;
  if(k == 0)      v = ws[O_X2 + b*NV + n];
  else if(k == 1) v = mask[(size_t)(b*NV+n)*TT + t];
  else            v = ws[O_H + ((size_t)(b*64+k-2))*NV + n];
  ws[O_XH + g] = v;
}

__global__ __launch_bounds__(256) void k_sprop66(float* __restrict__ ws, int srcF, int srcB,
                                                 int dstF, int dstB){
  int g = blockIdx.x*blockDim.x + threadIdx.x;
  if(g >= BB*66*NV) return;
  int b = g/(66*NV); int rem = g - b*66*NV; int k = rem>>10, w = rem&1023;
  const int* ccnt = (const int*)(ws + O_CCNT);
  const float* sF = ws + srcF + (size_t)(b*66+k)*NV;
  const float* sB = ws + srcB + (size_t)(b*66+k)*NV;
  float pf = 0.f, pb = 0.f;
  { int cn = ccnt[w];
    const int* id = (const int*)(ws+O_CIDX) + (size_t)w*CAP;
    const float* vl = ws + O_CVAL + (size_t)w*CAP;
    for(int kk=0;kk<cn;++kk) pf += vl[kk]*sF[id[kk]]; }
  { int cn = ccnt[NV+w];
    const int* id = (const int*)(ws+O_CIDX) + (size_t)(NV+w)*CAP;
    const float* vl = ws + O_CVAL + (size_t)(NV+w)*CAP;
    for(int kk=0;kk<cn;++kk) pb += vl[kk]*sB[id[kk]]; }
  ws[dstF + g] = pf;
  ws[dstB + g] = pb;
}

__global__ __launch_bounds__(256) void k_gates(float* __restrict__ ws,
    const float* __restrict__ fW, const float* __restrict__ fb,
    const float* __restrict__ uW, const float* __restrict__ ub){
  int g = blockIdx.x*blockDim.x + threadIdx.x;
  if(g >= BB*64*NV) return;
  int b = g>>16, c = (g>>10)&63, n = g&1023;
  const int fo[5] = {O_XH, O_Z1F, O_Z2F, O_Z1B, O_Z2B};
  float ar = fb[c], au = ub[c];
  for(int f=0; f<5; ++f){
    const float* fld = ws + fo[f] + (size_t)(b*66)*NV;
    for(int k=0;k<66;++k){
      float xv = fld[(size_t)k*NV + n];
      ar += fW[c*330 + f*66 + k]*xv;
      au += uW[c*330 + f*66 + k]*xv;
    }
  }
  float r = 1.f/(1.f + expf(-ar));
  float u = 1.f/(1.f + expf(-au));
  ws[O_U + g] = u;
  ws[O_XC + ((size_t)(b*66 + 2 + c))*NV + n] = r * ws[O_H + ((size_t)(b*64+c))*NV + n];
  if(c == 0) ws[O_XC + ((size_t)(b*66))*NV + n]   = ws[O_XH + ((size_t)(b*66))*NV + n];
  if(c == 1) ws[O_XC + ((size_t)(b*66+1))*NV + n] = ws[O_XH + ((size_t)(b*66+1))*NV + n];
}

__global__ __launch_bounds__(256) void k_cand(float* __restrict__ ws,
    const float* __restrict__ cW, const float* __restrict__ cb){
  int g = blockIdx.x*blockDim.x + threadIdx.x;
  if(g >= BB*64*NV) return;
  int b = g>>16, c = (g>>10)&63, n = g&1023;
  const int fo[5] = {O_XC, O_Z1F, O_Z2F, O_Z1B, O_Z2B};
  float ac = cb[c];
  for(int f=0; f<5; ++f){
    const float* fld = ws + fo[f] + (size_t)(b*66)*NV;
    for(int k=0;k<66;++k) ac += cW[c*330 + f*66 + k] * fld[(size_t)k*NV + n];
  }
  float cd = tanhf(ac);
  float h = ws[O_H + g];
  float u = ws[O_U + g];
  ws[O_H + g] = u*h + (1.f - u)*cd;
}

__global__ __launch_bounds__(1024) void k_stats(float* __restrict__ ws){
  __shared__ float rs[1024], rq[1024];
  int b = blockIdx.x, n = threadIdx.x;
  float s = 0.f, q = 0.f;
  for(int c=0;c<64;++c){
    float v = ws[O_H + ((size_t)(b*64+c))*NV + n];
    s += v; q += v*v;
  }
  rs[n] = s; rq[n] = q; __syncthreads();
  for(int st=512; st>0; st>>=1){
    if(n < st){ rs[n] += rs[n+st]; rq[n] += rq[n+st]; }
    __syncthreads();
  }
  if(n == 0){ ws[O_STATS + 2*b] = rs[0]; ws[O_STATS + 2*b+1] = rq[0]; }
}

__global__ __launch_bounds__(256) void k_norm(float* __restrict__ ws,
    const float* __restrict__ gng, const float* __restrict__ gnb, int t){
  int g = blockIdx.x*blockDim.x + threadIdx.x;
  if(g >= BB*64*NV) return;
  int b = g>>16, c = (g>>10)&63, n = g&1023;
  float mu = ws[O_STATS + 2*b] * (1.f/65536.f);
  float var = ws[O_STATS + 2*b+1] * (1.f/65536.f) - mu*mu;
  float h = (ws[O_H + g] - mu) * rsqrtf(var + 1e-5f) * gng[c] + gnb[c];
  ws[O_H + g] = h;
  ((bf16*)(ws + O_SST))[(((size_t)t*BB + b)*NV + n)*64 + c] = f2b(h);
}

// transpose staging bf16 [t][b][n][CH] -> output f32 [b][CH][n][T]
__global__ __launch_bounds__(256) void k_transpose(const float* __restrict__ ws, float* __restrict__ dout,
                                                   int srcOff, int dstOff, int CH){
  __shared__ bf16 ld[32][16][26];
  int ct = CH/16;
  int per_b = 32*ct;
  int b = blockIdx.x / per_b;
  int r = blockIdx.x - b*per_b;
  int n0 = (r/ct)*32, ch0 = (r - (r/ct)*ct)*16;
  const bf16* src = (const bf16*)(ws + srcOff);
  for(int t=0;t<TT;++t){
    for(int i=threadIdx.x;i<512;i+=256){
      int cc=i&15, nn=i>>4;
      ld[nn][cc][t] = src[(((size_t)t*BB + b)*NV + n0+nn)*CH + ch0+cc];
    }
  }
  __syncthreads();
  for(int i=threadIdx.x;i<512;i+=256){
    int nn=i&31, cc=i>>5;
    size_t ob = ((size_t)(b*CH + ch0+cc)*NV + n0+nn)*TT;
    #pragma unroll
    for(int t=0;t<TT;++t) dout[dstOff + ob + t] = b2f(ld[nn][cc][t]);
  }
}

extern "C" void kernel_launch(void* const* d_in, const int* in_sizes, int n_in,
                              void* d_out, int out_size, void* d_ws, size_t ws_size,
                              hipStream_t stream){
  if(ws_size < WS_FLOATS * sizeof(float)) return;
  if(n_in < 23) return;

  float* ws = (float*)d_ws;
  float* out = (float*)d_out;

  const float* x    = (const float*)d_in[0];
  const float* mask = (const float*)d_in[1];
  const float* adj  = (const float*)d_in[2];
  const float* h0   = (const float*)d_in[3];
  const float* fsW  = (const float*)d_in[4];
  const float* fsb  = (const float*)d_in[5];
  const float* liW  = (const float*)d_in[6];
  const float* lib  = (const float*)d_in[7];
  const float* gcW  = (const float*)d_in[8];
  const float* gcb  = (const float*)d_in[9];
  const float* loW  = (const float*)d_in[10];
  const float* lob  = (const float*)d_in[11];
  const float* roW  = (const float*)d_in[12];
  const float* rob  = (const float*)d_in[13];
  const float* prelu= (const float*)d_in[14];
  const float* fW   = (const float*)d_in[15];
  const float* fb   = (const float*)d_in[16];
  const float* uW   = (const float*)d_in[17];
  const float* ub   = (const float*)d_in[18];
  const float* cW   = (const float*)d_in[19];
  const float* cb   = (const float*)d_in[20];
  const float* gng  = (const float*)d_in[21];
  const float* gnb  = (const float*)d_in[22];

  k_csr<<<dim3(8), dim3(256), 0, stream>>>(adj, ws);
  k_h0 <<<dim3(2048), dim3(256), 0, stream>>>(h0, ws);

  for(int t=0; t<TT; ++t){
    k_pred   <<<dim3(32),   dim3(256), 0, stream>>>(ws, x, mask, fsW, fsb, out, t);
    k_xin    <<<dim3(2048), dim3(256), 0, stream>>>(ws, mask, liW, lib, t);
    k_sprop64<<<dim3(2048), dim3(256), 0, stream>>>(ws);
    k_gc     <<<dim3(2048), dim3(256), 0, stream>>>(ws, gcW, gcb);
    k_lo     <<<dim3(2048), dim3(256), 0, stream>>>(ws, loW, lob, prelu, t);
    k_ro     <<<dim3(32),   dim3(256), 0, stream>>>(ws, x, mask, roW, rob, out, t);
    k_xh     <<<dim3(2112), dim3(256), 0, stream>>>(ws, mask, t);
    k_sprop66<<<dim3(2112), dim3(256), 0, stream>>>(ws, O_XH,  O_XH,  O_Z1F, O_Z1B);
    k_sprop66<<<dim3(2112), dim3(256), 0, stream>>>(ws, O_Z1F, O_Z1B, O_Z2F, O_Z2B);
    k_gates  <<<dim3(2048), dim3(256), 0, stream>>>(ws, fW, fb, uW, ub);
    k_sprop66<<<dim3(2112), dim3(256), 0, stream>>>(ws, O_XC,  O_XC,  O_Z1F, O_Z1B);
    k_sprop66<<<dim3(2112), dim3(256), 0, stream>>>(ws, O_Z1F, O_Z1B, O_Z2F, O_Z2B);
    k_cand   <<<dim3(2048), dim3(256), 0, stream>>>(ws, cW, cb);
    k_stats  <<<dim3(8),    dim3(1024),0, stream>>>(ws);
    k_norm   <<<dim3(2048), dim3(256), 0, stream>>>(ws, gng, gnb, t);
  }

  k_transpose<<<dim3(2048), dim3(256), 0, stream>>>(ws, out, O_RST, OFF_REPR, 128);
  k_transpose<<<dim3(1024), dim3(256), 0, stream>>>(ws, out, O_SST, OFF_ST, 64);
}

// Round 9
// 7513.354 us; speedup vs baseline: 4.8356x; 4.8356x over previous
//
#include <hip/hip_runtime.h>
#include <hip/hip_bf16.h>

typedef __hip_bfloat16 bf16;

constexpr int NV=1024, TT=24, BB=8, CAP=80;

// ---- ws layout (float offsets) ---- node-major fields [b][n][C]
constexpr int O_CVAL = 0;               // 2048*80
constexpr int O_CIDX = 163840;          // 2048*80 ints
constexpr int O_CCNT = 327680;          // 2048 ints
constexpr int O_LIWT = 329728;          // 66*64  (k-major: [k][c])
constexpr int O_GCWT = 333952;          // 128*64
constexpr int O_LOWT = 342144;          // 128*64
constexpr int O_FWT  = 350336;          // 330*64
constexpr int O_UWT  = 371456;          // 330*64
constexpr int O_CWT  = 392576;          // 330*64 -> end 413696
constexpr int O_H    = 413696;          // [b][n][64]
constexpr int O_T1   = 937984;          // xin -> gcv   ; XC aliases here
constexpr int O_T2   = 1462272;         // P -> out
constexpr int O_T3   = 1986560;         // Q ; U aliases here
constexpr int O_XH   = 2510848;         // [b][n][68] (66 used)
constexpr int O_Z1F  = 3067904;
constexpr int O_Z1B  = 3624960;
constexpr int O_Z2F  = 4182016;
constexpr int O_Z2B  = 4739072;
constexpr int O_STATS= 5296128;         // 16
constexpr int O_RST  = 5296144;         // bf16 [24][8][1024][128]
constexpr int O_SST  = 17879056;        // bf16 [24][8][1024][64]
constexpr size_t WS_FLOATS = 24170512;  // 96.7 MB  (< round-8's 25.09M, known OK)
constexpr int O_XC = O_T1;              // alias: T1..T2-head dead when XC live
constexpr int O_U  = O_T3;              // alias: Q dead after k_gc

// ---- output layout (f32 elements) ----
constexpr int OFF_IMP  = 0;
constexpr int OFF_PRED = 196608;
constexpr int OFF_REPR = 393216;
constexpr int OFF_ST   = 25559040;

__device__ __forceinline__ bf16 f2b(float v){ return __float2bfloat16(v); }
__device__ __forceinline__ float b2f(bf16 v){ return __bfloat162float(v); }

// wave-ballot CSR build: one wave per adjacency row (coalesced)
__global__ __launch_bounds__(64) void k_csr(const float* __restrict__ adj, float* __restrict__ ws){
  int row = blockIdx.x, lane = threadIdx.x;
  const float* a = adj + (size_t)row*NV;
  float* val = ws + O_CVAL + (size_t)row*CAP;
  int* idx = (int*)(ws+O_CIDX) + (size_t)row*CAP;
  int count = 0;
  for(int ch=0; ch<NV/64; ++ch){
    float v = a[ch*64+lane];
    unsigned long long m = __ballot(v != 0.f);
    int pre = __popcll(m & ((1ull<<lane)-1ull));
    if(v != 0.f){ int p = count+pre; if(p<CAP){ idx[p]=ch*64+lane; val[p]=v; } }
    count += __popcll(m);
  }
  if(lane==0) ((int*)(ws+O_CCNT))[row] = count>CAP?CAP:count;
}

// k-transpose the 6 weight matrices into ws (coalesced reads later)
__global__ void k_prep_wt(const float* __restrict__ liW, const float* __restrict__ gcW,
    const float* __restrict__ loW, const float* __restrict__ fW,
    const float* __restrict__ uW, const float* __restrict__ cW, float* __restrict__ ws){
  int g = blockIdx.x*blockDim.x + threadIdx.x, G = gridDim.x*blockDim.x;
  for(int i=g;i<66*64;i+=G){ int k=i>>6, c=i&63; ws[O_LIWT+i]=liW[c*66+k]; }
  for(int i=g;i<128*64;i+=G){ int k=i>>6, c=i&63; ws[O_GCWT+i]=gcW[c*128+k]; ws[O_LOWT+i]=loW[c*128+k]; }
  for(int i=g;i<330*64;i+=G){ int k=i>>6, c=i&63; ws[O_FWT+i]=fW[c*330+k]; ws[O_UWT+i]=uW[c*330+k]; ws[O_CWT+i]=cW[c*330+k]; }
}

__global__ __launch_bounds__(256) void k_h0(const float* __restrict__ h0, float* __restrict__ ws){
  int g = blockIdx.x*blockDim.x + threadIdx.x;
  if(g >= BB*NV*64) return;
  int c = g&63, n = (g>>6)&1023;
  ws[O_H + g] = h0[c*NV + n];   // node-major
}

// fused: pred (+output), x1, xin -> T1.  one wave per column (b,n)
__global__ __launch_bounds__(256) void k_xin(float* __restrict__ ws,
    const float* __restrict__ x, const float* __restrict__ mask,
    const float* __restrict__ fsW, const float* __restrict__ fsb,
    const float* __restrict__ lib, float* __restrict__ dout, int t){
  __shared__ float hs[4][64];
  int wid = threadIdx.x>>6, lane = threadIdx.x&63;
  int col = blockIdx.x*4 + wid;
  float hv = ws[O_H + (size_t)col*64 + lane];
  hs[wid][lane] = hv;
  float pv = fsW[lane]*hv;
  #pragma unroll
  for(int off=32; off; off>>=1) pv += __shfl_xor(pv, off, 64);
  float pred = pv + fsb[0];
  float xm = mask[(size_t)col*TT + t];
  float x1 = (xm>0.f) ? x[(size_t)col*TT + t] : pred;
  if(lane==0) dout[OFF_PRED + (size_t)col*TT + t] = pred;
  __syncthreads();
  const float* Wt = ws + O_LIWT;
  float acc = lib[lane] + Wt[lane]*x1 + Wt[64+lane]*xm;
  #pragma unroll 8
  for(int j=0;j<64;++j) acc += Wt[(2+j)*64+lane]*hs[wid][j];
  ws[O_T1 + (size_t)col*64 + lane] = acc;
}

// sparse prop, wave-per-row: dstF = fwd(srcF), dstB = bwd(srcB). stride S, nch channels
__global__ __launch_bounds__(256) void k_prop(float* __restrict__ ws, int srcF, int srcB,
    int dstF, int dstB, int S, int nch){
  int wid = threadIdx.x>>6, lane = threadIdx.x&63;
  int row = blockIdx.x*4 + wid;
  int b = row>>10, w = row&1023;
  const int* ccnt = (const int*)(ws+O_CCNT);
  bool hi = lane < (nch-64);
  {
    int cn = ccnt[w];
    const int* id = (const int*)(ws+O_CIDX) + (size_t)w*CAP;
    const float* vl = ws + O_CVAL + (size_t)w*CAP;
    float a0=0.f, a1=0.f;
    for(int k=0;k<cn;++k){
      float a = vl[k];
      const float* r = ws + srcF + (size_t)(b*NV + id[k])*S;
      a0 += a*r[lane];
      if(hi) a1 += a*r[64+lane];
    }
    float* d = ws + dstF + (size_t)row*S;
    d[lane] = a0;
    if(hi) d[64+lane] = a1;
  }
  {
    int cn = ccnt[NV+w];
    const int* id = (const int*)(ws+O_CIDX) + (size_t)(NV+w)*CAP;
    const float* vl = ws + O_CVAL + (size_t)(NV+w)*CAP;
    float a0=0.f, a1=0.f;
    for(int k=0;k<cn;++k){
      float a = vl[k];
      const float* r = ws + srcB + (size_t)(b*NV + id[k])*S;
      a0 += a*r[lane];
      if(hi) a1 += a*r[64+lane];
    }
    float* d = ws + dstB + (size_t)row*S;
    d[lane] = a0;
    if(hi) d[64+lane] = a1;
  }
}

// gcv = gc_b + gcW·[P,Q]  -> T1 (overwrites xin, dead)
__global__ __launch_bounds__(256) void k_gc(float* __restrict__ ws, const float* __restrict__ gcb){
  __shared__ float pq[4][128];
  int wid=threadIdx.x>>6, lane=threadIdx.x&63;
  int col = blockIdx.x*4+wid;
  pq[wid][lane]    = ws[O_T2 + (size_t)col*64 + lane];
  pq[wid][64+lane] = ws[O_T3 + (size_t)col*64 + lane];
  __syncthreads();
  const float* Wt = ws + O_GCWT;
  float acc = gcb[lane];
  #pragma unroll 8
  for(int j=0;j<128;++j) acc += Wt[j*64+lane]*pq[wid][j];
  ws[O_T1 + (size_t)col*64 + lane] = acc;
}

// fused: lo+PReLU -> repr staging ; ro -> imputation ; x2 ; build XH
__global__ __launch_bounds__(256) void k_lo_ro(float* __restrict__ ws,
    const float* __restrict__ x, const float* __restrict__ mask,
    const float* __restrict__ lob, const float* __restrict__ prelu,
    const float* __restrict__ roW, const float* __restrict__ rob,
    float* __restrict__ dout, int t){
  __shared__ float gh[4][128];
  int wid=threadIdx.x>>6, lane=threadIdx.x&63;
  int col = blockIdx.x*4+wid;
  int b = col>>10, n = col&1023;
  float hv = ws[O_H + (size_t)col*64 + lane];
  gh[wid][lane]    = ws[O_T1 + (size_t)col*64 + lane];
  gh[wid][64+lane] = hv;
  __syncthreads();
  const float* Wt = ws + O_LOWT;
  float acc = lob[lane];
  #pragma unroll 8
  for(int j=0;j<128;++j) acc += Wt[j*64+lane]*gh[wid][j];
  float a = prelu[0];
  float o = (acc>=0.f)? acc : a*acc;
  bf16* reprs = (bf16*)(ws + O_RST);
  size_t rb = (((size_t)t*BB + b)*NV + n)*128;
  reprs[rb + lane]      = f2b(o);
  reprs[rb + 64 + lane] = f2b(hv);
  float rv = roW[lane]*o + roW[64+lane]*hv;
  #pragma unroll
  for(int off=32; off; off>>=1) rv += __shfl_xor(rv, off, 64);
  float xs2 = rv + rob[0];
  float xm = mask[(size_t)col*TT+t];
  float x2 = (xm>0.f) ? x[(size_t)col*TT+t] : xs2;
  if(lane==0) dout[OFF_IMP + (size_t)col*TT + t] = xs2;
  float* xh = ws + O_XH + (size_t)col*68;
  xh[2+lane] = hv;
  if(lane==0){ xh[0]=x2; xh[1]=xm; }
}

// gates r,u from [XH,Z1F,Z2F,Z1B,Z2B] ; U out ; build XC
__global__ __launch_bounds__(256) void k_gates(float* __restrict__ ws,
    const float* __restrict__ fb, const float* __restrict__ ub){
  __shared__ float vec[4][332];
  int wid=threadIdx.x>>6, lane=threadIdx.x&63;
  int col = blockIdx.x*4+wid;
  const int fo[5] = {O_XH, O_Z1F, O_Z2F, O_Z1B, O_Z2B};
  for(int i=lane;i<330;i+=64){
    int f=i/66, c=i-f*66;
    vec[wid][i] = ws[fo[f] + (size_t)col*68 + c];
  }
  __syncthreads();
  const float* Ft = ws + O_FWT;
  const float* Ut = ws + O_UWT;
  float ar = fb[lane], au = ub[lane];
  for(int k=0;k<330;++k){
    float v = vec[wid][k];
    ar += Ft[k*64+lane]*v;
    au += Ut[k*64+lane]*v;
  }
  float r = 1.f/(1.f+expf(-ar));
  float u = 1.f/(1.f+expf(-au));
  float hv = ws[O_H + (size_t)col*64 + lane];
  ws[O_U + (size_t)col*64 + lane] = u;
  float* xc = ws + O_XC + (size_t)col*68;
  xc[2+lane] = r*hv;
  if(lane<2) xc[lane] = ws[O_XH + (size_t)col*68 + lane];
}

// candidate + h_new -> H (pre-norm)
__global__ __launch_bounds__(256) void k_cand(float* __restrict__ ws, const float* __restrict__ cb){
  __shared__ float vec[4][332];
  int wid=threadIdx.x>>6, lane=threadIdx.x&63;
  int col = blockIdx.x*4+wid;
  const int fo[5] = {O_XC, O_Z1F, O_Z2F, O_Z1B, O_Z2B};
  for(int i=lane;i<330;i+=64){
    int f=i/66, c=i-f*66;
    vec[wid][i] = ws[fo[f] + (size_t)col*68 + c];
  }
  __syncthreads();
  const float* Ct = ws + O_CWT;
  float ac = cb[lane];
  for(int k=0;k<330;++k) ac += Ct[k*64+lane]*vec[wid][k];
  float cd = tanhf(ac);
  float hv = ws[O_H + (size_t)col*64+lane];
  float u  = ws[O_U + (size_t)col*64+lane];
  ws[O_H + (size_t)col*64+lane] = u*hv + (1.f-u)*cd;
}

// per-batch stats over pre-norm H
__global__ __launch_bounds__(1024) void k_stats(float* __restrict__ ws){
  __shared__ float rs[1024], rq[1024];
  int b = blockIdx.x, n = threadIdx.x;
  const float* hrow = ws + O_H + (size_t)(b*NV+n)*64;
  float s=0.f, q=0.f;
  for(int c=0;c<64;++c){ float v=hrow[c]; s+=v; q+=v*v; }
  rs[n]=s; rq[n]=q; __syncthreads();
  for(int st=512; st; st>>=1){ if(n<st){ rs[n]+=rs[n+st]; rq[n]+=rq[n+st]; } __syncthreads(); }
  if(n==0){ ws[O_STATS+2*b]=rs[0]; ws[O_STATS+2*b+1]=rq[0]; }
}

// normalize H in place ; stage states bf16
__global__ __launch_bounds__(256) void k_norm(float* __restrict__ ws,
    const float* __restrict__ gng, const float* __restrict__ gnb, int t){
  int g = blockIdx.x*blockDim.x + threadIdx.x;
  if(g >= BB*NV*64) return;
  int c = g&63, b = g>>16;
  float mu = ws[O_STATS + 2*b] * (1.f/65536.f);
  float var = ws[O_STATS + 2*b+1] * (1.f/65536.f) - mu*mu;
  float h = (ws[O_H + g] - mu) * rsqrtf(var + 1e-5f) * gng[c] + gnb[c];
  ws[O_H + g] = h;
  ((bf16*)(ws + O_SST))[(size_t)t*(BB*NV*64) + g] = f2b(h);
}

// transpose staging bf16 [t][b][n][CH] -> output f32 [b][CH][n][T]
__global__ __launch_bounds__(256) void k_transpose(const float* __restrict__ ws, float* __restrict__ dout,
                                                   int srcOff, int dstOff, int CH){
  __shared__ bf16 ld[32][16][26];
  int ct = CH/16;
  int per_b = 32*ct;
  int b = blockIdx.x / per_b;
  int r = blockIdx.x - b*per_b;
  int n0 = (r/ct)*32, ch0 = (r - (r/ct)*ct)*16;
  const bf16* src = (const bf16*)(ws + srcOff);
  for(int t=0;t<TT;++t){
    for(int i=threadIdx.x;i<512;i+=256){
      int cc=i&15, nn=i>>4;
      ld[nn][cc][t] = src[(((size_t)t*BB + b)*NV + n0+nn)*CH + ch0+cc];
    }
  }
  __syncthreads();
  for(int i=threadIdx.x;i<512;i+=256){
    int nn=i&31, cc=i>>5;
    size_t ob = ((size_t)(b*CH + ch0+cc)*NV + n0+nn)*TT;
    #pragma unroll
    for(int t=0;t<TT;++t) dout[dstOff + ob + t] = b2f(ld[nn][cc][t]);
  }
}

extern "C" void kernel_launch(void* const* d_in, const int* in_sizes, int n_in,
                              void* d_out, int out_size, void* d_ws, size_t ws_size,
                              hipStream_t stream){
  if(ws_size < WS_FLOATS * sizeof(float)) return;
  if(n_in < 23) return;

  float* ws = (float*)d_ws;
  float* out = (float*)d_out;

  const float* x    = (const float*)d_in[0];
  const float* mask = (const float*)d_in[1];
  const float* adj  = (const float*)d_in[2];
  const float* h0   = (const float*)d_in[3];
  const float* fsW  = (const float*)d_in[4];
  const float* fsb  = (const float*)d_in[5];
  const float* liW  = (const float*)d_in[6];
  const float* lib  = (const float*)d_in[7];
  const float* gcW  = (const float*)d_in[8];
  const float* gcb  = (const float*)d_in[9];
  const float* loW  = (const float*)d_in[10];
  const float* lob  = (const float*)d_in[11];
  const float* roW  = (const float*)d_in[12];
  const float* rob  = (const float*)d_in[13];
  const float* prelu= (const float*)d_in[14];
  const float* fW   = (const float*)d_in[15];
  const float* fb   = (const float*)d_in[16];
  const float* uW   = (const float*)d_in[17];
  const float* ub   = (const float*)d_in[18];
  const float* cW   = (const float*)d_in[19];
  const float* cb   = (const float*)d_in[20];
  const float* gng  = (const float*)d_in[21];
  const float* gnb  = (const float*)d_in[22];

  k_csr    <<<dim3(2048), dim3(64),  0, stream>>>(adj, ws);
  k_prep_wt<<<dim3(64),   dim3(256), 0, stream>>>(liW, gcW, loW, fW, uW, cW, ws);
  k_h0     <<<dim3(2048), dim3(256), 0, stream>>>(h0, ws);

  for(int t=0; t<TT; ++t){
    k_xin  <<<dim3(2048), dim3(256), 0, stream>>>(ws, x, mask, fsW, fsb, lib, out, t);
    k_prop <<<dim3(2048), dim3(256), 0, stream>>>(ws, O_T1, O_T1, O_T2, O_T3, 64, 64);
    k_gc   <<<dim3(2048), dim3(256), 0, stream>>>(ws, gcb);
    k_lo_ro<<<dim3(2048), dim3(256), 0, stream>>>(ws, x, mask, lob, prelu, roW, rob, out, t);
    k_prop <<<dim3(2048), dim3(256), 0, stream>>>(ws, O_XH,  O_XH,  O_Z1F, O_Z1B, 68, 66);
    k_prop <<<dim3(2048), dim3(256), 0, stream>>>(ws, O_Z1F, O_Z1B, O_Z2F, O_Z2B, 68, 66);
    k_gates<<<dim3(2048), dim3(256), 0, stream>>>(ws, fb, ub);
    k_prop <<<dim3(2048), dim3(256), 0, stream>>>(ws, O_XC,  O_XC,  O_Z1F, O_Z1B, 68, 66);
    k_prop <<<dim3(2048), dim3(256), 0, stream>>>(ws, O_Z1F, O_Z1B, O_Z2F, O_Z2B, 68, 66);
    k_cand <<<dim3(2048), dim3(256), 0, stream>>>(ws, cb);
    k_stats<<<dim3(8),    dim3(1024),0, stream>>>(ws);
    k_norm <<<dim3(2048), dim3(256), 0, stream>>>(ws, gng, gnb, t);
  }

  k_transpose<<<dim3(2048), dim3(256), 0, stream>>>(ws, out, O_RST, OFF_REPR, 128);
  k_transpose<<<dim3(1024), dim3(256), 0, stream>>>(ws, out, O_SST, OFF_ST, 64);
}

// Round 10
// 6585.390 us; speedup vs baseline: 5.5170x; 1.1409x over previous
//
#include <hip/hip_runtime.h>
#include <hip/hip_bf16.h>

typedef __hip_bfloat16 bf16;

constexpr int NV=1024, TT=24, BB=8, CAP=80;

// ---- ws layout (float offsets) ---- node-major fields [b][n][C]
constexpr int O_CVAL = 0;               // 2048*80
constexpr int O_CIDX = 163840;          // 2048*80 ints
constexpr int O_CCNT = 327680;          // 2048 ints
constexpr int O_LIWT = 329728;          // 66*64  k-major [k][c]
constexpr int O_GCWT = 333952;          // 128*64
constexpr int O_LOWT = 342144;          // 128*64
constexpr int O_FWT  = 350336;          // 330*64
constexpr int O_UWT  = 371456;          // 330*64
constexpr int O_CWT  = 392576;          // 330*64
constexpr int O_H    = 413696;          // [b][n][64]
constexpr int O_T1   = 937984;          // xin
constexpr int O_T3   = 1986560;         // U
constexpr int O_XH   = 2510848;         // [b][n][68] (66 used)
constexpr int O_Z1F  = 3067904;
constexpr int O_Z1B  = 3624960;
constexpr int O_PART = 4182016;         // [8][256] float2 partial (sum,sumsq)
constexpr int O_STATS= 5296128;         // (unused now)
constexpr int O_RST  = 5296144;         // bf16 [24][8][1024][128]
constexpr int O_SST  = 17879056;        // bf16 [24][8][1024][64]
constexpr size_t WS_FLOATS = 24170512;
constexpr int O_XC = O_T1;              // alias: xin dead when XC live
constexpr int O_U  = O_T3;

// ---- output layout (f32 elements) ----
constexpr int OFF_IMP  = 0;
constexpr int OFF_PRED = 196608;
constexpr int OFF_REPR = 393216;
constexpr int OFF_ST   = 25559040;

__device__ __forceinline__ bf16 f2b(float v){ return __float2bfloat16(v); }
__device__ __forceinline__ float b2f(bf16 v){ return __bfloat162float(v); }

__global__ __launch_bounds__(64) void k_csr(const float* __restrict__ adj, float* __restrict__ ws){
  int row = blockIdx.x, lane = threadIdx.x;
  const float* a = adj + (size_t)row*NV;
  float* val = ws + O_CVAL + (size_t)row*CAP;
  int* idx = (int*)(ws+O_CIDX) + (size_t)row*CAP;
  int count = 0;
  for(int ch=0; ch<NV/64; ++ch){
    float v = a[ch*64+lane];
    unsigned long long m = __ballot(v != 0.f);
    int pre = __popcll(m & ((1ull<<lane)-1ull));
    if(v != 0.f){ int p = count+pre; if(p<CAP){ idx[p]=ch*64+lane; val[p]=v; } }
    count += __popcll(m);
  }
  if(lane==0) ((int*)(ws+O_CCNT))[row] = count>CAP?CAP:count;
}

__global__ void k_prep_wt(const float* __restrict__ liW, const float* __restrict__ gcW,
    const float* __restrict__ loW, const float* __restrict__ fW,
    const float* __restrict__ uW, const float* __restrict__ cW, float* __restrict__ ws){
  int g = blockIdx.x*blockDim.x + threadIdx.x, G = gridDim.x*blockDim.x;
  for(int i=g;i<66*64;i+=G){ int k=i>>6, c=i&63; ws[O_LIWT+i]=liW[c*66+k]; }
  for(int i=g;i<128*64;i+=G){ int k=i>>6, c=i&63; ws[O_GCWT+i]=gcW[c*128+k]; ws[O_LOWT+i]=loW[c*128+k]; }
  for(int i=g;i<330*64;i+=G){ int k=i>>6, c=i&63; ws[O_FWT+i]=fW[c*330+k]; ws[O_UWT+i]=uW[c*330+k]; ws[O_CWT+i]=cW[c*330+k]; }
}

__global__ __launch_bounds__(256) void k_h0(const float* __restrict__ h0, float* __restrict__ ws){
  int g = blockIdx.x*blockDim.x + threadIdx.x;
  if(g >= BB*NV*64) return;
  int c = g&63, n = (g>>6)&1023;
  ws[O_H + g] = h0[c*NV + n];
}

// kA: finalize GroupNorm(t-1) from partials + stage states ; pred ; xin -> T1
__global__ __launch_bounds__(256) void kA(float* __restrict__ ws,
    const float* __restrict__ x, const float* __restrict__ mask,
    const float* __restrict__ fsW, const float* __restrict__ fsb,
    const float* __restrict__ lib, const float* __restrict__ gng,
    const float* __restrict__ gnb, float* __restrict__ dout, int t){
  __shared__ float hs[4][64];
  __shared__ float red[256];
  __shared__ float mv[2];
  int tid = threadIdx.x, wid = tid>>6, lane = tid&63;
  int col = blockIdx.x*4 + wid;
  int b = col>>10;
  if(t > 0){
    float2 p = ((const float2*)(ws+O_PART))[b*256 + tid];
    red[tid] = p.x; __syncthreads();
    for(int s=128;s;s>>=1){ if(tid<s) red[tid]+=red[tid+s]; __syncthreads(); }
    if(tid==0) mv[0] = red[0]*(1.f/65536.f);
    __syncthreads();
    red[tid] = p.y; __syncthreads();
    for(int s=128;s;s>>=1){ if(tid<s) red[tid]+=red[tid+s]; __syncthreads(); }
    if(tid==0){ float mu=mv[0]; mv[1] = rsqrtf(red[0]*(1.f/65536.f)-mu*mu + 1e-5f); }
    __syncthreads();
    float mu = mv[0], ri = mv[1];
    float hn = ws[O_H + (size_t)col*64 + lane];
    float h = (hn-mu)*ri*gng[lane] + gnb[lane];
    ws[O_H + (size_t)col*64 + lane] = h;
    ((bf16*)(ws+O_SST))[(size_t)(t-1)*(BB*NV*64) + (size_t)col*64 + lane] = f2b(h);
    hs[wid][lane] = h;
  } else {
    hs[wid][lane] = ws[O_H + (size_t)col*64 + lane];
  }
  __syncthreads();
  float hv = hs[wid][lane];
  float pv = fsW[lane]*hv;
  #pragma unroll
  for(int off=32; off; off>>=1) pv += __shfl_xor(pv, off, 64);
  float pred = pv + fsb[0];
  float xm = mask[(size_t)col*TT + t];
  float x1 = (xm>0.f) ? x[(size_t)col*TT + t] : pred;
  if(lane==0) dout[OFF_PRED + (size_t)col*TT + t] = pred;
  const float* Wt = ws + O_LIWT;
  float acc = lib[lane] + Wt[lane]*x1 + Wt[64+lane]*xm;
  #pragma unroll 8
  for(int j=0;j<64;++j) acc += Wt[(2+j)*64+lane]*hs[wid][j];
  ws[O_T1 + (size_t)col*64 + lane] = acc;
}

// kB: prop64(T1)->P,Q (regs/LDS) ; gc ; lo+PReLU -> repr ; ro -> imp ; x2 ; build XH
__global__ __launch_bounds__(256) void kB(float* __restrict__ ws,
    const float* __restrict__ x, const float* __restrict__ mask,
    const float* __restrict__ gcb, const float* __restrict__ lob,
    const float* __restrict__ prelu, const float* __restrict__ roW,
    const float* __restrict__ rob, float* __restrict__ dout, int t){
  __shared__ float pq[4][128];
  int tid=threadIdx.x, wid=tid>>6, lane=tid&63;
  int col = blockIdx.x*4+wid;
  int b = col>>10, w = col&1023, n = w;
  const int* ccnt = (const int*)(ws+O_CCNT);
  float p=0.f, q=0.f;
  {
    int cn = ccnt[w];
    const int* id = (const int*)(ws+O_CIDX) + (size_t)w*CAP;
    const float* vl = ws + O_CVAL + (size_t)w*CAP;
    for(int k=0;k<cn;++k) p += vl[k]*ws[O_T1 + (size_t)(b*NV+id[k])*64 + lane];
  }
  {
    int cn = ccnt[NV+w];
    const int* id = (const int*)(ws+O_CIDX) + (size_t)(NV+w)*CAP;
    const float* vl = ws + O_CVAL + (size_t)(NV+w)*CAP;
    for(int k=0;k<cn;++k) q += vl[k]*ws[O_T1 + (size_t)(b*NV+id[k])*64 + lane];
  }
  pq[wid][lane]=p; pq[wid][64+lane]=q;
  __syncthreads();
  const float* Gt = ws + O_GCWT;
  float acc = gcb[lane];
  #pragma unroll 8
  for(int j=0;j<128;++j) acc += Gt[j*64+lane]*pq[wid][j];
  float hv = ws[O_H + (size_t)col*64 + lane];
  __syncthreads();
  pq[wid][lane]=acc; pq[wid][64+lane]=hv;
  __syncthreads();
  const float* Lt = ws + O_LOWT;
  float o = lob[lane];
  #pragma unroll 8
  for(int j=0;j<128;++j) o += Lt[j*64+lane]*pq[wid][j];
  float a = prelu[0];
  o = (o>=0.f)? o : a*o;
  bf16* reprs = (bf16*)(ws + O_RST);
  size_t rb = (((size_t)t*BB + b)*NV + n)*128;
  reprs[rb + lane]      = f2b(o);
  reprs[rb + 64 + lane] = f2b(hv);
  float rv = roW[lane]*o + roW[64+lane]*hv;
  #pragma unroll
  for(int off=32; off; off>>=1) rv += __shfl_xor(rv, off, 64);
  float xs2 = rv + rob[0];
  float xm = mask[(size_t)col*TT+t];
  float x2 = (xm>0.f) ? x[(size_t)col*TT+t] : xs2;
  if(lane==0) dout[OFF_IMP + (size_t)col*TT + t] = xs2;
  float* xh = ws + O_XH + (size_t)col*68;
  xh[2+lane] = hv;
  if(lane==0){ xh[0]=x2; xh[1]=xm; }
}

// first-order prop66: dstF = fwd(srcF), dstB = bwd(srcB)
__global__ __launch_bounds__(256) void k_prop(float* __restrict__ ws, int srcF, int srcB,
    int dstF, int dstB){
  int wid = threadIdx.x>>6, lane = threadIdx.x&63;
  int row = blockIdx.x*4 + wid;
  int b = row>>10, w = row&1023;
  const int* ccnt = (const int*)(ws+O_CCNT);
  bool hi = lane < 2;
  {
    int cn = ccnt[w];
    const int* id = (const int*)(ws+O_CIDX) + (size_t)w*CAP;
    const float* vl = ws + O_CVAL + (size_t)w*CAP;
    float a0=0.f, a1=0.f;
    for(int k=0;k<cn;++k){
      float a = vl[k];
      const float* r = ws + srcF + (size_t)(b*NV + id[k])*68;
      a0 += a*r[lane];
      if(hi) a1 += a*r[64+lane];
    }
    float* d = ws + dstF + (size_t)row*68;
    d[lane] = a0;
    if(hi) d[64+lane] = a1;
  }
  {
    int cn = ccnt[NV+w];
    const int* id = (const int*)(ws+O_CIDX) + (size_t)(NV+w)*CAP;
    const float* vl = ws + O_CVAL + (size_t)(NV+w)*CAP;
    float a0=0.f, a1=0.f;
    for(int k=0;k<cn;++k){
      float a = vl[k];
      const float* r = ws + srcB + (size_t)(b*NV + id[k])*68;
      a0 += a*r[lane];
      if(hi) a1 += a*r[64+lane];
    }
    float* d = ws + dstB + (size_t)row*68;
    d[lane] = a0;
    if(hi) d[64+lane] = a1;
  }
}

// kD: gates. stage [XH,Z1F,Z1B] own col; gather Z2F,Z2B on the fly; 330-dot x2 ; U ; XC
__global__ __launch_bounds__(256) void kD(float* __restrict__ ws,
    const float* __restrict__ fb, const float* __restrict__ ub){
  __shared__ float vec[4][332];
  int tid=threadIdx.x, wid=tid>>6, lane=tid&63;
  int col = blockIdx.x*4+wid;
  int b = col>>10, w = col&1023;
  const int* ccnt = (const int*)(ws+O_CCNT);
  const float* xh  = ws + O_XH  + (size_t)col*68;
  const float* z1f = ws + O_Z1F + (size_t)col*68;
  const float* z1b = ws + O_Z1B + (size_t)col*68;
  vec[wid][lane]     = xh[lane];   if(lane<2) vec[wid][64+lane]  = xh[64+lane];
  vec[wid][66+lane]  = z1f[lane];  if(lane<2) vec[wid][130+lane] = z1f[64+lane];
  vec[wid][198+lane] = z1b[lane];  if(lane<2) vec[wid][262+lane] = z1b[64+lane];
  {
    int cn = ccnt[w];
    const int* id = (const int*)(ws+O_CIDX) + (size_t)w*CAP;
    const float* vl = ws + O_CVAL + (size_t)w*CAP;
    float a0=0.f, a1=0.f;
    for(int k=0;k<cn;++k){
      float a = vl[k];
      const float* r = ws + O_Z1F + (size_t)(b*NV+id[k])*68;
      a0 += a*r[lane];
      if(lane<2) a1 += a*r[64+lane];
    }
    vec[wid][132+lane]=a0; if(lane<2) vec[wid][196+lane]=a1;
  }
  {
    int cn = ccnt[NV+w];
    const int* id = (const int*)(ws+O_CIDX) + (size_t)(NV+w)*CAP;
    const float* vl = ws + O_CVAL + (size_t)(NV+w)*CAP;
    float a0=0.f, a1=0.f;
    for(int k=0;k<cn;++k){
      float a = vl[k];
      const float* r = ws + O_Z1B + (size_t)(b*NV+id[k])*68;
      a0 += a*r[lane];
      if(lane<2) a1 += a*r[64+lane];
    }
    vec[wid][264+lane]=a0; if(lane<2) vec[wid][328+lane]=a1;
  }
  __syncthreads();
  const float* Ft = ws + O_FWT;
  const float* Ut = ws + O_UWT;
  float ar = fb[lane], au = ub[lane];
  for(int k=0;k<330;++k){
    float v = vec[wid][k];
    ar += Ft[k*64+lane]*v;
    au += Ut[k*64+lane]*v;
  }
  float r = 1.f/(1.f+expf(-ar));
  float u = 1.f/(1.f+expf(-au));
  float hv = ws[O_H + (size_t)col*64 + lane];
  ws[O_U + (size_t)col*64 + lane] = u;
  float* xc = ws + O_XC + (size_t)col*68;
  xc[2+lane] = r*hv;
  if(lane<2) xc[lane] = xh[lane];
}

// kF: candidate. stage [XC,W1F,W1B]; gather W2F,W2B; 330-dot ; h_new ; per-block stats partial
__global__ __launch_bounds__(256) void kF(float* __restrict__ ws, const float* __restrict__ cb){
  __shared__ float vec[4][332];
  __shared__ float red[256];
  int tid=threadIdx.x, wid=tid>>6, lane=tid&63;
  int col = blockIdx.x*4+wid;
  int b = col>>10, w = col&1023;
  const int* ccnt = (const int*)(ws+O_CCNT);
  const float* xc  = ws + O_XC  + (size_t)col*68;
  const float* w1f = ws + O_Z1F + (size_t)col*68;
  const float* w1b = ws + O_Z1B + (size_t)col*68;
  vec[wid][lane]     = xc[lane];   if(lane<2) vec[wid][64+lane]  = xc[64+lane];
  vec[wid][66+lane]  = w1f[lane];  if(lane<2) vec[wid][130+lane] = w1f[64+lane];
  vec[wid][198+lane] = w1b[lane];  if(lane<2) vec[wid][262+lane] = w1b[64+lane];
  {
    int cn = ccnt[w];
    const int* id = (const int*)(ws+O_CIDX) + (size_t)w*CAP;
    const float* vl = ws + O_CVAL + (size_t)w*CAP;
    float a0=0.f, a1=0.f;
    for(int k=0;k<cn;++k){
      float a = vl[k];
      const float* r = ws + O_Z1F + (size_t)(b*NV+id[k])*68;
      a0 += a*r[lane];
      if(lane<2) a1 += a*r[64+lane];
    }
    vec[wid][132+lane]=a0; if(lane<2) vec[wid][196+lane]=a1;
  }
  {
    int cn = ccnt[NV+w];
    const int* id = (const int*)(ws+O_CIDX) + (size_t)(NV+w)*CAP;
    const float* vl = ws + O_CVAL + (size_t)(NV+w)*CAP;
    float a0=0.f, a1=0.f;
    for(int k=0;k<cn;++k){
      float a = vl[k];
      const float* r = ws + O_Z1B + (size_t)(b*NV+id[k])*68;
      a0 += a*r[lane];
      if(lane<2) a1 += a*r[64+lane];
    }
    vec[wid][264+lane]=a0; if(lane<2) vec[wid][328+lane]=a1;
  }
  __syncthreads();
  const float* Ct = ws + O_CWT;
  float ac = cb[lane];
  for(int k=0;k<330;++k) ac += Ct[k*64+lane]*vec[wid][k];
  float cd = tanhf(ac);
  float hv = ws[O_H + (size_t)col*64 + lane];
  float u  = ws[O_U + (size_t)col*64 + lane];
  float hn = u*hv + (1.f-u)*cd;
  ws[O_H + (size_t)col*64 + lane] = hn;
  red[tid] = hn; __syncthreads();
  for(int s=128;s;s>>=1){ if(tid<s) red[tid]+=red[tid+s]; __syncthreads(); }
  float bs = red[0];
  __syncthreads();
  red[tid] = hn*hn; __syncthreads();
  for(int s=128;s;s>>=1){ if(tid<s) red[tid]+=red[tid+s]; __syncthreads(); }
  if(tid==0){
    ((float2*)(ws+O_PART))[b*256 + (blockIdx.x & 255)] = make_float2(bs, red[0]);
  }
}

// final: normalize t=23 states from partials
__global__ __launch_bounds__(256) void k_final(float* __restrict__ ws,
    const float* __restrict__ gng, const float* __restrict__ gnb){
  __shared__ float red[256];
  __shared__ float mv[2];
  int tid=threadIdx.x, wid=tid>>6, lane=tid&63;
  int col = blockIdx.x*4+wid;
  int b = col>>10;
  float2 p = ((const float2*)(ws+O_PART))[b*256 + tid];
  red[tid] = p.x; __syncthreads();
  for(int s=128;s;s>>=1){ if(tid<s) red[tid]+=red[tid+s]; __syncthreads(); }
  if(tid==0) mv[0] = red[0]*(1.f/65536.f);
  __syncthreads();
  red[tid] = p.y; __syncthreads();
  for(int s=128;s;s>>=1){ if(tid<s) red[tid]+=red[tid+s]; __syncthreads(); }
  if(tid==0){ float mu=mv[0]; mv[1] = rsqrtf(red[0]*(1.f/65536.f)-mu*mu + 1e-5f); }
  __syncthreads();
  float mu = mv[0], ri = mv[1];
  float hn = ws[O_H + (size_t)col*64 + lane];
  float h = (hn-mu)*ri*gng[lane] + gnb[lane];
  ((bf16*)(ws+O_SST))[(size_t)23*(BB*NV*64) + (size_t)col*64 + lane] = f2b(h);
}

// transpose staging bf16 [t][b][n][CH] -> output f32 [b][CH][n][T]
__global__ __launch_bounds__(256) void k_transpose(const float* __restrict__ ws, float* __restrict__ dout,
                                                   int srcOff, int dstOff, int CH){
  __shared__ bf16 ld[32][16][26];
  int ct = CH/16;
  int per_b = 32*ct;
  int b = blockIdx.x / per_b;
  int r = blockIdx.x - b*per_b;
  int n0 = (r/ct)*32, ch0 = (r - (r/ct)*ct)*16;
  const bf16* src = (const bf16*)(ws + srcOff);
  for(int t=0;t<TT;++t){
    for(int i=threadIdx.x;i<512;i+=256){
      int cc=i&15, nn=i>>4;
      ld[nn][cc][t] = src[(((size_t)t*BB + b)*NV + n0+nn)*CH + ch0+cc];
    }
  }
  __syncthreads();
  for(int i=threadIdx.x;i<512;i+=256){
    int nn=i&31, cc=i>>5;
    size_t ob = ((size_t)(b*CH + ch0+cc)*NV + n0+nn)*TT;
    #pragma unroll
    for(int t=0;t<TT;++t) dout[dstOff + ob + t] = b2f(ld[nn][cc][t]);
  }
}

extern "C" void kernel_launch(void* const* d_in, const int* in_sizes, int n_in,
                              void* d_out, int out_size, void* d_ws, size_t ws_size,
                              hipStream_t stream){
  if(ws_size < WS_FLOATS * sizeof(float)) return;
  if(n_in < 23) return;

  float* ws = (float*)d_ws;
  float* out = (float*)d_out;

  const float* x    = (const float*)d_in[0];
  const float* mask = (const float*)d_in[1];
  const float* adj  = (const float*)d_in[2];
  const float* h0   = (const float*)d_in[3];
  const float* fsW  = (const float*)d_in[4];
  const float* fsb  = (const float*)d_in[5];
  const float* liW  = (const float*)d_in[6];
  const float* lib  = (const float*)d_in[7];
  const float* gcW  = (const float*)d_in[8];
  const float* gcb  = (const float*)d_in[9];
  const float* loW  = (const float*)d_in[10];
  const float* lob  = (const float*)d_in[11];
  const float* roW  = (const float*)d_in[12];
  const float* rob  = (const float*)d_in[13];
  const float* prelu= (const float*)d_in[14];
  const float* fW   = (const float*)d_in[15];
  const float* fb   = (const float*)d_in[16];
  const float* uW   = (const float*)d_in[17];
  const float* ub   = (const float*)d_in[18];
  const float* cW   = (const float*)d_in[19];
  const float* cb   = (const float*)d_in[20];
  const float* gng  = (const float*)d_in[21];
  const float* gnb  = (const float*)d_in[22];

  k_csr    <<<dim3(2048), dim3(64),  0, stream>>>(adj, ws);
  k_prep_wt<<<dim3(64),   dim3(256), 0, stream>>>(liW, gcW, loW, fW, uW, cW, ws);
  k_h0     <<<dim3(2048), dim3(256), 0, stream>>>(h0, ws);

  for(int t=0; t<TT; ++t){
    kA    <<<dim3(2048), dim3(256), 0, stream>>>(ws, x, mask, fsW, fsb, lib, gng, gnb, out, t);
    kB    <<<dim3(2048), dim3(256), 0, stream>>>(ws, x, mask, gcb, lob, prelu, roW, rob, out, t);
    k_prop<<<dim3(2048), dim3(256), 0, stream>>>(ws, O_XH, O_XH, O_Z1F, O_Z1B);
    kD    <<<dim3(2048), dim3(256), 0, stream>>>(ws, fb, ub);
    k_prop<<<dim3(2048), dim3(256), 0, stream>>>(ws, O_XC, O_XC, O_Z1F, O_Z1B);
    kF    <<<dim3(2048), dim3(256), 0, stream>>>(ws, cb);
  }
  k_final<<<dim3(2048), dim3(256), 0, stream>>>(ws, gng, gnb);

  k_transpose<<<dim3(2048), dim3(256), 0, stream>>>(ws, out, O_RST, OFF_REPR, 128);
  k_transpose<<<dim3(1024), dim3(256), 0, stream>>>(ws, out, O_SST, OFF_ST, 64);
}